// Round 9
// baseline (2284.659 us; speedup 1.0000x reference)
//
#include <hip/hip_runtime.h>
#include <hip/hip_bf16.h>
#include <stdint.h>

typedef unsigned short u16;
typedef __bf16 bf16x8 __attribute__((ext_vector_type(8)));
typedef float f32x4 __attribute__((ext_vector_type(4)));

#define NWIN 4096
#define NTOK 49
#define CDIM 384
#define NHEAD 12
#define HD 32
#define MROWS (NWIN * NTOK)   // 200704
#define QKVN (3 * CDIM)       // 1152
#define GK 384                // K of both GEMMs (compile-time)
#define GNT 12                // GK / 32  (BK=32)
#define SCALE 0.17677669529663689f

__device__ __forceinline__ u16 f2bf(float f) {
  uint32_t u = __float_as_uint(f);
  u += 0x7fff + ((u >> 16) & 1);   // RNE
  return (u16)(u >> 16);
}

__device__ __forceinline__ void gload_lds16(const void* g, void* l) {
  __builtin_amdgcn_global_load_lds(
      (const __attribute__((address_space(1))) unsigned int*)g,
      (__attribute__((address_space(3))) unsigned int*)l, 16, 0, 0);
}

// ---------------- prep kernels ----------------

__global__ __launch_bounds__(256) void cvt_x_kernel(const float* __restrict__ x,
                                                    u16* __restrict__ xb, int n4) {
  int i = blockIdx.x * blockDim.x + threadIdx.x;
  int stride = gridDim.x * blockDim.x;
  for (; i < n4; i += stride) {
    float4 v = ((const float4*)x)[i];
    ushort4 o;
    o.x = f2bf(v.x); o.y = f2bf(v.y); o.z = f2bf(v.z); o.w = f2bf(v.w);
    ((ushort4*)xb)[i] = o;
  }
}

// w[K][N] (f32) -> wT[N][K] (bf16)
__global__ __launch_bounds__(256) void cvt_wT_kernel(const float* __restrict__ w,
                                                     u16* __restrict__ wT, int K, int N) {
  int i = blockIdx.x * blockDim.x + threadIdx.x;
  if (i >= K * N) return;
  int n = i / K, k = i - n * K;
  wT[i] = f2bf(w[k * N + n]);
}

// bias12p[12][64][64] = bias_table[rel_index]+mask, zero-padded to 64x64
__global__ __launch_bounds__(256) void build_bias_kernel(const float* __restrict__ bt,
                                                         const int* __restrict__ ri,
                                                         const float* __restrict__ mask,
                                                         float* __restrict__ bias12p) {
  int i = blockIdx.x * blockDim.x + threadIdx.x;
  if (i >= NHEAD * 64 * 64) return;
  int h = i >> 12, r = (i >> 6) & 63, c = i & 63;
  float v = 0.f;
  if (r < NTOK && c < NTOK) v = bt[ri[r * NTOK + c] * NHEAD + h] + mask[r * NTOK + c];
  bias12p[i] = v;
}

// ---------------- 128x128 bf16 MFMA GEMM, BK=32 high-occupancy ----------------
// LDS 32 KB/block -> 5 blocks/CU (20 waves, ~62% occ) to hide ds_read/load latency.
// Depth-2 counted-vmcnt pipeline (vmcnt(4), never 0 until last tile), raw barriers.
// T2 both-sides swizzle for 64-B rows: chunk' = fg ^ ((row>>1)&3)  (uniform 8 quads).
// A [M][GK] bf16 row-major, BT [N][GK] bf16 row-major. Grid % 8 == 0.
// MODE 0: QKV epilogue (scatter q/k/vT, q scaled). MODE 1: f32 out + bias.

template <int MODE>
__device__ __forceinline__ void gemm_body(const u16* __restrict__ A,
                                          const u16* __restrict__ BT,
                                          const float* __restrict__ bias,
                                          float* __restrict__ outF,
                                          u16* __restrict__ q_ws,
                                          u16* __restrict__ k_ws,
                                          u16* __restrict__ vT_ws,
                                          int n_tiles) {
  __shared__ __align__(16) u16 As[2][128 * 32];
  __shared__ __align__(16) u16 Bs[2][128 * 32];
  const int tid = threadIdx.x;
  const int wave = tid >> 6, lane = tid & 63;

  // XCD-chunked bijective swizzle (grid % 8 == 0)
  const int nwg = gridDim.x;
  int bid = blockIdx.x;
  bid = (bid & 7) * (nwg >> 3) + (bid >> 3);

  const int mt = bid / n_tiles, ntile = bid - mt * n_tiles;
  const int m0 = mt << 7, n0 = ntile << 7;
  const int fr = lane & 15, fg = lane >> 4;
  const int wr = (wave >> 1) << 6, wc = (wave & 1) << 6;

  f32x4 acc[4][4] = {};

  // chunk c in [0,512) per matrix: row=c>>2, col4=c&3; source col pre-swizzled
  auto stage = [&](int k0s, int bufi) {
#pragma unroll
    for (int it = 0; it < 2; ++it) {
      const int c = it * 256 + tid;
      const int row = c >> 2, col4 = c & 3;
      const int scol = ((col4 ^ ((row >> 1) & 3)) << 3);
      gload_lds16(A + (size_t)(m0 + row) * GK + k0s + scol, &As[bufi][c * 8]);
    }
#pragma unroll
    for (int it = 0; it < 2; ++it) {
      const int c = it * 256 + tid;
      const int row = c >> 2, col4 = c & 3;
      const int scol = ((col4 ^ ((row >> 1) & 3)) << 3);
      gload_lds16(BT + (size_t)(n0 + row) * GK + k0s + scol, &Bs[bufi][c * 8]);
    }
  };

  stage(0, 0);    // 4 loads/thread: tile 0
  stage(32, 1);   // 4 loads/thread: tile 1  (8 outstanding)

  const int swz = fg ^ ((fr >> 1) & 3);   // read-side involution (row>>1)&3 == (fr>>1)&3

#pragma unroll
  for (int t = 0; t < GNT; ++t) {
    if (t < GNT - 1) asm volatile("s_waitcnt vmcnt(4)" ::: "memory");
    else             asm volatile("s_waitcnt vmcnt(0)" ::: "memory");
    __builtin_amdgcn_s_barrier();

    const int buf = t & 1;
    bf16x8 av[4], bv[4];
#pragma unroll
    for (int i = 0; i < 4; ++i)
      av[i] = *(const bf16x8*)((const char*)&As[buf][0] + (size_t)(wr + i * 16 + fr) * 64 + (swz << 4));
#pragma unroll
    for (int i = 0; i < 4; ++i)
      bv[i] = *(const bf16x8*)((const char*)&Bs[buf][0] + (size_t)(wc + i * 16 + fr) * 64 + (swz << 4));
    __builtin_amdgcn_s_setprio(1);
#pragma unroll
    for (int i = 0; i < 4; ++i)
#pragma unroll
      for (int j = 0; j < 4; ++j)
        acc[i][j] = __builtin_amdgcn_mfma_f32_16x16x32_bf16(av[i], bv[j], acc[i][j], 0, 0, 0);
    __builtin_amdgcn_s_setprio(0);

    // all waves done reading buf -> safe to DMA-overwrite with tile t+2
    __builtin_amdgcn_s_barrier();
    if (t + 2 < GNT) stage((t + 2) << 5, buf);
  }

  // ---------------- epilogue ----------------
  const int col0 = n0 + wc + fr;
  float bvadd[4];
#pragma unroll
  for (int j = 0; j < 4; ++j) bvadd[j] = bias[col0 + j * 16];

  if (MODE == 0) {
    const int s = col0 / CDIM;   // wave-uniform (64-col span never straddles 384)
    int hh[4], dd[4];
#pragma unroll
    for (int j = 0; j < 4; ++j) {
      const int cr = col0 + j * 16 - s * CDIM;
      hh[j] = cr >> 5; dd[j] = cr & 31;
    }
#pragma unroll
    for (int i = 0; i < 4; ++i) {
#pragma unroll
      for (int r = 0; r < 4; ++r) {
        const int row_g = m0 + wr + i * 16 + fg * 4 + r;
        const int b = row_g / NTOK, n = row_g - b * NTOK;   // once per row
        const size_t bhb = (size_t)b * NHEAD;
#pragma unroll
        for (int j = 0; j < 4; ++j) {
          const float v = acc[i][j][r] + bvadd[j];
          const size_t bh = bhb + hh[j];
          if (s == 0)      q_ws[(bh * NTOK + n) * HD + dd[j]] = f2bf(v * SCALE);
          else if (s == 1) k_ws[(bh * NTOK + n) * HD + dd[j]] = f2bf(v);
          else             vT_ws[(bh * HD + dd[j]) * 64 + n] = f2bf(v);
        }
      }
    }
  } else {
#pragma unroll
    for (int i = 0; i < 4; ++i) {
#pragma unroll
      for (int r = 0; r < 4; ++r) {
        const int row_g = m0 + wr + i * 16 + fg * 4 + r;
        float* op = outF + (size_t)row_g * CDIM + col0;
#pragma unroll
        for (int j = 0; j < 4; ++j) op[j * 16] = acc[i][j][r] + bvadd[j];
      }
    }
  }
}

// distinct symbols so rocprof attributes QKV vs proj separately
__global__ __launch_bounds__(256, 5) void gemm_qkv(const u16* __restrict__ A,
                                                   const u16* __restrict__ BT,
                                                   const float* __restrict__ bias,
                                                   u16* __restrict__ q_ws,
                                                   u16* __restrict__ k_ws,
                                                   u16* __restrict__ vT_ws,
                                                   int n_tiles) {
  gemm_body<0>(A, BT, bias, nullptr, q_ws, k_ws, vT_ws, n_tiles);
}

__global__ __launch_bounds__(256, 5) void gemm_proj(const u16* __restrict__ A,
                                                    const u16* __restrict__ BT,
                                                    const float* __restrict__ bias,
                                                    float* __restrict__ outF,
                                                    int n_tiles) {
  gemm_body<1>(A, BT, bias, outF, nullptr, nullptr, nullptr, n_tiles);
}

// ---------------- attention: one wave per (window, head) ----------------
// v3: union LDS buffer (S f32 [64][67] reused for P bf16 stride-72) -> 17 KB/block
// -> 9 blocks/CU. V prefetched to regs; single-pass register softmax.

__global__ __launch_bounds__(64, 2) void attn_kernel(const u16* __restrict__ q_ws,
                                                     const u16* __restrict__ k_ws,
                                                     const u16* __restrict__ vT_ws,
                                                     const float* __restrict__ bias12p,
                                                     u16* __restrict__ att_ws) {
  __shared__ __align__(16) float SP[64 * 67];   // S f32; later overlaid by P bf16 [64][72]
  u16* P = (u16*)SP;
  const int bh = blockIdx.x;
  const int b = bh / NHEAD, h = bh - b * NHEAD;
  const int lane = threadIdx.x;
  const int fr = lane & 15, fg = lane >> 4;
  const u16* qp = q_ws + (size_t)bh * NTOK * HD;
  const u16* kp = k_ws + (size_t)bh * NTOK * HD;
  const u16* vp = vT_ws + (size_t)bh * HD * 64;

  // --- prefetch V fragments early (independent of everything before PV) ---
  bf16x8 bv[2][2];
#pragma unroll
  for (int kt = 0; kt < 2; ++kt)
#pragma unroll
    for (int n2 = 0; n2 < 2; ++n2)
      bv[kt][n2] = *(const bf16x8*)&vp[(n2 * 16 + fr) * 64 + kt * 32 + fg * 8];

  // --- QK^T ---
  bf16x8 aq[4], bk[4];
#pragma unroll
  for (int i = 0; i < 4; ++i) {
    int m = i * 16 + fr;
    m = m < NTOK ? m : NTOK - 1;           // clamped duplicate rows, masked later
    aq[i] = *(const bf16x8*)&qp[m * HD + fg * 8];
    bk[i] = *(const bf16x8*)&kp[m * HD + fg * 8];
  }
  f32x4 sacc[4][4] = {};
#pragma unroll
  for (int i = 0; i < 4; ++i)
#pragma unroll
    for (int j = 0; j < 4; ++j)
      sacc[i][j] = __builtin_amdgcn_mfma_f32_16x16x32_bf16(aq[i], bk[j], sacc[i][j], 0, 0, 0);

  const float* bp = bias12p + h * 64 * 64;
#pragma unroll
  for (int i = 0; i < 4; ++i)
#pragma unroll
    for (int j = 0; j < 4; ++j)
#pragma unroll
      for (int r = 0; r < 4; ++r) {
        const int row = i * 16 + fg * 4 + r, col = j * 16 + fr;
        SP[row * 67 + col] = sacc[i][j][r] + bp[row * 64 + col];
      }
  __syncthreads();

  // --- read own row fully into regs (then S region may be overwritten) ---
  const int r = lane;
  float sv[49];
#pragma unroll
  for (int j = 0; j < 49; ++j) sv[j] = SP[r * 67 + j];
  __syncthreads();   // all lanes captured their S row; P may overlay now

  // --- single-pass softmax in regs ---
  float mx = sv[0];
#pragma unroll
  for (int j = 1; j < 49; ++j) mx = fmaxf(mx, sv[j]);
  float s0 = 0.f, s1 = 0.f;
#pragma unroll
  for (int j = 0; j < 48; j += 2) {
    sv[j]     = __expf(sv[j] - mx);     s0 += sv[j];
    sv[j + 1] = __expf(sv[j + 1] - mx); s1 += sv[j + 1];
  }
  sv[48] = __expf(sv[48] - mx); s0 += sv[48];
  const float inv = (r < NTOK) ? 1.f / (s0 + s1) : 0.f;  // zeroes pad rows, branch-free
#pragma unroll
  for (int c = 0; c < 8; ++c) {
    uint32_t w[4];
#pragma unroll
    for (int u = 0; u < 4; ++u) {
      const int j0 = c * 8 + u * 2, j1 = j0 + 1;
      const uint32_t lo = (j0 < 49) ? (uint32_t)f2bf(sv[j0] * inv) : 0u;
      const uint32_t hi = (j1 < 49) ? (uint32_t)f2bf(sv[j1] * inv) : 0u;
      w[u] = lo | (hi << 16);
    }
    *(uint4*)&P[r * 72 + c * 8] = make_uint4(w[0], w[1], w[2], w[3]);
  }
  __syncthreads();

  // --- PV: O[49][32] = P[64][64] @ v[64][32] (B fragments already in regs) ---
  f32x4 oacc[4][2] = {};
#pragma unroll
  for (int kt = 0; kt < 2; ++kt) {
    bf16x8 ap[4];
#pragma unroll
    for (int i = 0; i < 4; ++i)
      ap[i] = *(const bf16x8*)&P[(i * 16 + fr) * 72 + kt * 32 + fg * 8];
#pragma unroll
    for (int i = 0; i < 4; ++i)
#pragma unroll
      for (int n2 = 0; n2 < 2; ++n2)
        oacc[i][n2] = __builtin_amdgcn_mfma_f32_16x16x32_bf16(ap[i], bv[kt][n2], oacc[i][n2], 0, 0, 0);
  }
  u16* ao = att_ws + ((size_t)b * NTOK) * CDIM + h * HD;
#pragma unroll
  for (int i = 0; i < 4; ++i)
#pragma unroll
    for (int n2 = 0; n2 < 2; ++n2)
#pragma unroll
      for (int rr = 0; rr < 4; ++rr) {
        const int row = i * 16 + fg * 4 + rr, col = n2 * 16 + fr;
        if (row < NTOK) ao[(size_t)row * CDIM + col] = f2bf(oacc[i][n2][rr]);
      }
}

// ---------------- launch ----------------

extern "C" void kernel_launch(void* const* d_in, const int* in_sizes, int n_in,
                              void* d_out, int out_size, void* d_ws, size_t ws_size,
                              hipStream_t stream) {
  (void)in_sizes; (void)n_in; (void)out_size; (void)ws_size;
  const float* x      = (const float*)d_in[0];
  const float* mask   = (const float*)d_in[1];
  const float* qkv_w  = (const float*)d_in[2];
  const float* qkv_b  = (const float*)d_in[3];
  const float* proj_w = (const float*)d_in[4];
  const float* proj_b = (const float*)d_in[5];
  const float* btab   = (const float*)d_in[6];
  const int*   ridx   = (const int*)d_in[7];
  float* out = (float*)d_out;

  char* ws = (char*)d_ws;
  size_t off = 0;
  auto alloc = [&](size_t bytes) {
    char* p = ws + off;
    off = (off + bytes + 255) & ~(size_t)255;
    return p;
  };
  u16* q_ws    = (u16*)alloc((size_t)NWIN * NHEAD * NTOK * HD * 2);  // 154 MB
  u16* k_ws    = (u16*)alloc((size_t)NWIN * NHEAD * NTOK * HD * 2);  // 154 MB
  u16* vT_ws   = (u16*)alloc((size_t)NWIN * NHEAD * HD * 64 * 2);    // 201 MB (n padded to 64)
  u16* att_ws  = (u16*)alloc((size_t)MROWS * CDIM * 2);              // 154 MB
  u16* qkvWT   = (u16*)alloc((size_t)QKVN * CDIM * 2);
  u16* projWT  = (u16*)alloc((size_t)CDIM * CDIM * 2);
  float* bias12p = (float*)alloc((size_t)NHEAD * 64 * 64 * 4);

  u16* x_bf = (u16*)d_out;  // scratch: x in bf16 lives in d_out until final GEMM overwrites it

  cvt_x_kernel<<<4096, 256, 0, stream>>>(x, x_bf, MROWS * CDIM / 4);
  cvt_wT_kernel<<<(QKVN * CDIM + 255) / 256, 256, 0, stream>>>(qkv_w, qkvWT, CDIM, QKVN);
  cvt_wT_kernel<<<(CDIM * CDIM + 255) / 256, 256, 0, stream>>>(proj_w, projWT, CDIM, CDIM);
  build_bias_kernel<<<(NHEAD * 64 * 64 + 255) / 256, 256, 0, stream>>>(btab, ridx, mask, bias12p);

  gemm_qkv<<<(MROWS / 128) * (QKVN / 128), 256, 0, stream>>>(
      x_bf, qkvWT, qkv_b, q_ws, k_ws, vT_ws, QKVN / 128);

  attn_kernel<<<NWIN * NHEAD, 64, 0, stream>>>(q_ws, k_ws, vT_ws, bias12p, att_ws);

  gemm_proj<<<(MROWS / 128) * (CDIM / 128), 256, 0, stream>>>(
      att_ws, projWT, proj_b, out, CDIM / 128);
}